// Round 3
// baseline (2980.487 us; speedup 1.0000x reference)
//
#include <hip/hip_runtime.h>

// ============================================================================
// CNF log-density, fused persistent kernel — v4: 32x32x16 MFMA, val+tan fused.
//   - A-fragment rows 0-15 = value z, rows 16-31 = tangent eps: ONE MFMA per
//     (kt,nt) computes both GEMMs. MFMA count halves vs 16x16; tangent scale
//     (1-h^2)*t is lane-local (reg r+8 = row r+16 of same lane).
//   - Weights staged block-cooperatively in 8KB chunks (dbuf), 1 barrier per
//     chunk, loads issued one chunk ahead. Weight layout = contiguous chunk
//     stream of 40 x 8KB, so the chunk loop is flat across layers/fevals.
//   - Wave-private half-transpose buffer (32x136 bf16): prev-layer acc is
//     transposed to A-layout in two 128-col halves, freeing regs early.
//   - RK state: k1,k3 in regs (bf16), k2/k4/k5/k6 in 3 wave-private bf16
//     LDS slabs. RK loop flattened: one feval instantiation, stage switch.
//   - LDS 78848B -> 2 blocks/CU; target <=256 unified regs (no spill).
// ============================================================================

#define DIM   64
#define HID   256
#define BATCH 32768
#define LOG2PI_HALF_SUM 58.8120661251f   // 32 * log(2*pi)

typedef float  floatx4  __attribute__((ext_vector_type(4)));
typedef float  floatx16 __attribute__((ext_vector_type(16)));
typedef short  short8   __attribute__((ext_vector_type(8)));

// ---- workspace: bf16 weights, fragment-linear, contiguous 40-chunk stream ----
// chunk g = bytes [g*8192, (g+1)*8192): W1 g0-3, W2 g4-19, W3 g20-35, W4 g36-39
#define BOFF   327680    // biases fp32: b1[256] b2[256] b3[256] b4[64]
#define NCHUNK 40

// ---- LDS ----
#define TB_STRIDE   136              // shorts per tb row (128 + 8 pad)
#define SLAB_STRIDE 72               // shorts per slab row (64 + 8 pad)
#define SLAB_SH     1152             // shorts per slab (16*72)
#define SLABOFF     8704             // tb bytes: 32*136*2
#define WAVELDS     15616            // tb + 3 slabs (8704 + 6912)
#define DBUF_BYTES  16384            // 2 x 8KB weight chunks
#define SMEM_BYTES  (DBUF_BYTES + 4 * WAVELDS)   // 78848 -> 2 blocks/CU

#define MFMA32(a, b, c) __builtin_amdgcn_mfma_f32_32x32x16_bf16(a, b, c, 0, 0, 0)

__device__ __forceinline__ short f2bf(float f) {
    union { float f; unsigned u; } v; v.f = f;
    unsigned r = v.u + 0x7FFFu + ((v.u >> 16) & 1u);   // RTNE
    return (short)(r >> 16);
}

__device__ __forceinline__ float bf2f(short s) {
    union { float f; unsigned u; } v;
    v.u = ((unsigned)(unsigned short)s) << 16;
    return v.f;
}

__device__ __forceinline__ float fast_tanh(float x) {
    float e = __expf(2.0f * x);
    return 1.0f - 2.0f * __builtin_amdgcn_rcpf(e + 1.0f);
}

// ---- chunk staging: load next chunk to regs early, ds_write late ----
__device__ __forceinline__ void stage_ld(const char* __restrict__ ws, int gn,
                                         uint4& ra, uint4& rb) {
    const char* p = ws + gn * 8192 + threadIdx.x * 16;
    ra = *(const uint4*)p;
    rb = *(const uint4*)(p + 4096);
}
__device__ __forceinline__ void stage_st(char* dbuf, int gnext, uint4 ra, uint4 rb) {
    char* p = dbuf + (gnext & 1) * 8192 + threadIdx.x * 16;
    *(uint4*)p = ra;
    *(uint4*)(p + 4096) = rb;
}

// ---- transpose one 128-col half of prev-layer acc into tb (A-layout bf16) ----
// C layout: col = nt*32 + (l&31); row = (r&3) + 8*(r>>2) + 4*(l>>5).
// regs 0-7 = value rows 0-15 (apply tanh), regs 8-15 = tangent rows 16-31
// (scale by 1-h^2 using same-lane h).
__device__ __forceinline__ void write_half(const floatx16 (&src)[8], int h,
                                           short* tb, int l31, int hi) {
#pragma unroll
    for (int nt = 0; nt < 4; nt++) {
        const floatx16 a = src[4 * h + nt];
        const int cb = nt * 32 + l31;
#pragma unroll
        for (int r = 0; r < 8; r++) {
            const int rowv = (r & 3) + 8 * (r >> 2) + 4 * hi;
            float hv = fast_tanh(a[r]);
            float tv = (1.0f - hv * hv) * a[r + 8];
            tb[rowv * TB_STRIDE + cb]        = f2bf(hv);
            tb[(rowv + 16) * TB_STRIDE + cb] = f2bf(tv);
        }
    }
}

// ---- one hidden layer (K=256, N=256): 16 chunks, two A-halves ----
__device__ __forceinline__ void hid_layer(const floatx16 (&src)[8], floatx16 (&dst)[8],
                                          const float* bb, const char* __restrict__ ws,
                                          char* dbuf, short* tb, const int gbase,
                                          int lane, int l31, int hi) {
    const int fo = lane * 16;
#pragma unroll
    for (int nt = 0; nt < 8; nt++) {
        float b = bb[nt * 32 + l31];
        floatx16 c;
#pragma unroll
        for (int r = 0; r < 8; r++) { c[r] = b; c[r + 8] = 0.f; }
        dst[nt] = c;
    }
    write_half(src, 0, tb, l31, hi);
#pragma unroll
    for (int c = 0; c < 8; c++) {
        const int G = gbase + c;
        uint4 ra, rb; stage_ld(ws, G + 1, ra, rb);
        short8 a = *(const short8*)&tb[l31 * TB_STRIDE + c * 16 + hi * 8];
        const char* bp = dbuf + (G & 1) * 8192;
#pragma unroll
        for (int nt = 0; nt < 8; nt++) {
            short8 b = *(const short8*)(bp + nt * 1024 + fo);
            dst[nt] = MFMA32(a, b, dst[nt]);
        }
        stage_st(dbuf, G + 1, ra, rb);
        __syncthreads();
    }
    write_half(src, 1, tb, l31, hi);
#pragma unroll
    for (int c = 8; c < 16; c++) {
        const int G = gbase + c;
        uint4 ra, rb; stage_ld(ws, G + 1, ra, rb);
        short8 a = *(const short8*)&tb[l31 * TB_STRIDE + (c - 8) * 16 + hi * 8];
        const char* bp = dbuf + (G & 1) * 8192;
#pragma unroll
        for (int nt = 0; nt < 8; nt++) {
            short8 b = *(const short8*)(bp + nt * 1024 + fo);
            dst[nt] = MFMA32(a, b, dst[nt]);
        }
        stage_st(dbuf, G + 1, ra, rb);
        __syncthreads();
    }
}

// ---- one ODE f-eval: dz (bf16) -> slab[sout]; returns div (all lanes) ----
__device__ __forceinline__ float feval(const float (&zs)[16], short8 e0, short8 e1,
                                       const char* __restrict__ ws, char* dbuf,
                                       short* tb, short* slabs, int sout,
                                       int lane, int m, int kq) {
    const int l31 = lane & 31, hi = lane >> 5;
    const int fo = lane * 16;
    const float* bias = (const float*)(ws + BOFF);

    // layer-1 A source: rows 0-15 = zs (bf16), rows 16-31 = eps, dims 0-63
    short8 zlo, zhi;
#pragma unroll
    for (int j = 0; j < 8; j++) { zlo[j] = f2bf(zs[j]); zhi[j] = f2bf(zs[8 + j]); }
    *(short8*)&tb[m * TB_STRIDE + kq * 8]              = zlo;
    *(short8*)&tb[m * TB_STRIDE + 32 + kq * 8]         = zhi;
    *(short8*)&tb[(16 + m) * TB_STRIDE + kq * 8]       = e0;
    *(short8*)&tb[(16 + m) * TB_STRIDE + 32 + kq * 8]  = e1;

    floatx16 acc[8], acc2[8];

    // ---------------- layer 1: K=64 (4 kt), N=256, chunks 0-3 ----------------
#pragma unroll
    for (int nt = 0; nt < 8; nt++) {
        float b = bias[nt * 32 + l31];
        floatx16 c;
#pragma unroll
        for (int r = 0; r < 8; r++) { c[r] = b; c[r + 8] = 0.f; }
        acc[nt] = c;
    }
#pragma unroll
    for (int c = 0; c < 4; c++) {
        const int G = c;
        uint4 ra, rb; stage_ld(ws, G + 1, ra, rb);
        short8 a = *(const short8*)&tb[l31 * TB_STRIDE + c * 16 + hi * 8];
        const char* bp = dbuf + (G & 1) * 8192;
#pragma unroll
        for (int nt = 0; nt < 8; nt++) {
            short8 b = *(const short8*)(bp + nt * 1024 + fo);
            acc[nt] = MFMA32(a, b, acc[nt]);
        }
        stage_st(dbuf, G + 1, ra, rb);
        __syncthreads();
    }

    // ---------------- layers 2,3: chunks 4-19, 20-35 ----------------
    hid_layer(acc,  acc2, bias + 256, ws, dbuf, tb, 4,  lane, l31, hi);
    hid_layer(acc2, acc,  bias + 512, ws, dbuf, tb, 20, lane, l31, hi);

    // ---------------- layer 4: K=256 (16 kt), N=64, chunks 36-39 -------------
    floatx16 a4[2];
#pragma unroll
    for (int nt = 0; nt < 2; nt++) {
        float b = bias[768 + nt * 32 + l31];
        floatx16 c;
#pragma unroll
        for (int r = 0; r < 8; r++) { c[r] = b; c[r + 8] = 0.f; }
        a4[nt] = c;
    }
    write_half(acc, 0, tb, l31, hi);
#pragma unroll
    for (int c = 0; c < 2; c++) {
        const int G = 36 + c;
        uint4 ra, rb; stage_ld(ws, G + 1, ra, rb);
        const char* bp = dbuf + (G & 1) * 8192;
#pragma unroll
        for (int k4 = 0; k4 < 4; k4++) {
            short8 a = *(const short8*)&tb[l31 * TB_STRIDE + (c * 4 + k4) * 16 + hi * 8];
#pragma unroll
            for (int nt = 0; nt < 2; nt++) {
                short8 b = *(const short8*)(bp + (k4 * 2 + nt) * 1024 + fo);
                a4[nt] = MFMA32(a, b, a4[nt]);
            }
        }
        stage_st(dbuf, G + 1, ra, rb);
        __syncthreads();
    }
    write_half(acc, 1, tb, l31, hi);
#pragma unroll
    for (int c = 2; c < 4; c++) {
        const int G = 36 + c;
        const int gn = (G + 1 == NCHUNK) ? 0 : G + 1;   // wrap to next feval's chunk 0
        uint4 ra, rb; stage_ld(ws, gn, ra, rb);
        const char* bp = dbuf + (G & 1) * 8192;
#pragma unroll
        for (int k4 = 0; k4 < 4; k4++) {
            short8 a = *(const short8*)&tb[l31 * TB_STRIDE + ((c - 2) * 4 + k4) * 16 + hi * 8];
#pragma unroll
            for (int nt = 0; nt < 2; nt++) {
                short8 b = *(const short8*)(bp + (k4 * 2 + nt) * 1024 + fo);
                a4[nt] = MFMA32(a, b, a4[nt]);
            }
        }
        stage_st(dbuf, G + 1, ra, rb);
        __syncthreads();
    }

    // ---- epilogue: Jeps fp32 -> jb (tb overlay); dz bf16 -> slab[sout] ----
    float* jb = (float*)tb;                       // [16][68] floats
    short* sl = slabs + sout * SLAB_SH;
#pragma unroll
    for (int nt = 0; nt < 2; nt++)
#pragma unroll
        for (int r = 0; r < 8; r++) {
            const int rd = (r & 3) + 8 * (r >> 2) + 4 * hi;   // batch row 0..15
            jb[rd * 68 + nt * 32 + l31] = a4[nt][r + 8];      // Jeps row rd
            sl[rd * SLAB_STRIDE + nt * 32 + l31] = f2bf(a4[nt][r]);  // dz
        }
    float div = 0.f;
#pragma unroll
    for (int half = 0; half < 2; half++) {
        short8 ev = half ? e1 : e0;
#pragma unroll
        for (int q = 0; q < 2; q++) {
            floatx4 jv = *(const floatx4*)&jb[m * 68 + half * 32 + kq * 8 + q * 4];
#pragma unroll
            for (int j = 0; j < 4; j++) div += jv[j] * bf2f(ev[q * 4 + j]);
        }
    }
    div += __shfl_xor(div, 16, 64);
    div += __shfl_xor(div, 32, 64);
    return div;
}

#define SLO(s) (*(const short8*)&slabs[(s) * SLAB_SH + m * SLAB_STRIDE + kq * 8])
#define SHI(s) (*(const short8*)&slabs[(s) * SLAB_SH + m * SLAB_STRIDE + 32 + kq * 8])

__global__ void __launch_bounds__(256, 2)
cnf_main(const float* __restrict__ x, const float* __restrict__ eps,
         const char* __restrict__ ws, float* __restrict__ out) {
    extern __shared__ char smem[];
    const int tid  = threadIdx.x;
    const int lane = tid & 63;
    const int wave = tid >> 6;
    const int m = lane & 15, kq = lane >> 4;
    char*  dbuf  = smem;
    char*  wl    = smem + DBUF_BYTES + wave * WAVELDS;
    short* tb    = (short*)wl;
    short* slabs = (short*)(wl + SLABOFF);
    const int row = blockIdx.x * 64 + wave * 16 + m;

    // load x (fp32 regs) and eps (bf16 regs), (m,kq) layout: 16 dims each
    float y[16];
    short8 e0, e1;
#pragma unroll
    for (int kt = 0; kt < 2; kt++)
#pragma unroll
        for (int q = 0; q < 2; q++) {
            floatx4 vx = *(const floatx4*)(x   + row * DIM + kt * 32 + kq * 8 + q * 4);
            floatx4 ve = *(const floatx4*)(eps + row * DIM + kt * 32 + kq * 8 + q * 4);
#pragma unroll
            for (int j = 0; j < 4; j++) {
                y[kt * 8 + q * 4 + j] = vx[j];
                short b = f2bf(ve[j]);
                if (kt == 0) e0[q * 4 + j] = b; else e1[q * 4 + j] = b;
            }
        }

    // zero slabs (0-coeff combines must not FMA NaN garbage)
#pragma unroll
    for (int i = 0; i < 7; i++) {
        int idx = lane + i * 64;
        if (idx < 432) {
            short8 z = {0, 0, 0, 0, 0, 0, 0, 0};
            *(short8*)&slabs[idx * 8] = z;
        }
    }

    // prologue: stage chunk 0
    {
        uint4 ra, rb; stage_ld(ws, 0, ra, rb);
        stage_st(dbuf, 0, ra, rb);
        __syncthreads();
    }

    float ylogp = 0.f;
    short8 zero8 = {0, 0, 0, 0, 0, 0, 0, 0};
    short8 k1a = zero8, k1b = zero8, k3a = zero8, k3b = zero8;

#pragma unroll 1
    for (int st = 0; st < 24; st++) {
        const int stage = st % 6;
        float c1, c2, c3, c4, c5, bw; int sout;
        switch (stage) {
            case 0: c1=0.f;           c2=0.f;            c3=0.f;           c4=0.f;            c5=0.f;            bw=0.022786458f;  sout=0; break;
            case 1: c1=0.05f;         c2=0.f;            c3=0.f;           c4=0.f;            c5=0.f;            bw=0.f;           sout=0; break;
            case 2: c1=0.01875f;      c2=0.05625f;       c3=0.f;           c4=0.f;            c5=0.f;            bw=0.112309075f;  sout=1; break;
            case 3: c1=0.244444444f;  c2=-0.933333333f;  c3=0.888888889f;  c4=0.f;            c5=0.f;            bw=0.162760417f;  sout=1; break;
            case 4: c1=0.738149672f;  c2=-2.898948331f;  c3=2.455723213f;  c4=-0.072702332f;  c5=0.f;            bw=-0.080593989f; sout=2; break;
            default:c1=0.711568813f;  c2=-2.689393939f;  c3=2.226605679f;  c4=0.069602273f;   c5=-0.068382826f;  bw=0.032738095f;  sout=0; break;
        }

        // zs = y + c1 k1 + c2 k2(s0) + c3 k3 + c4 k4(s1) + c5 k5(s2)
        float zs[16];
        {
            short8 k2a = SLO(0), k2b = SHI(0);
            short8 k4a = SLO(1), k4b = SHI(1);
            short8 k5a = SLO(2), k5b = SHI(2);
#pragma unroll
            for (int j = 0; j < 8; j++) {
                zs[j]     = y[j]     + c1 * bf2f(k1a[j]) + c2 * bf2f(k2a[j])
                                     + c3 * bf2f(k3a[j]) + c4 * bf2f(k4a[j])
                                     + c5 * bf2f(k5a[j]);
                zs[8 + j] = y[8 + j] + c1 * bf2f(k1b[j]) + c2 * bf2f(k2b[j])
                                     + c3 * bf2f(k3b[j]) + c4 * bf2f(k4b[j])
                                     + c5 * bf2f(k5b[j]);
            }
        }

        const float d = feval(zs, e0, e1, ws, dbuf, tb, slabs, sout, lane, m, kq);

        if (stage == 0) { k1a = SLO(0); k1b = SHI(0); }   // k1 -> regs (slot 0 reused)
        if (stage == 2) { k3a = SLO(1); k3b = SHI(1); }   // k3 -> regs (slot 1 reused)
        if (stage == 5) {
            // y += b1 k1 + b3 k3 + b4 k4(s1) + b5 k5(s2) + b6 k6(s0)
            short8 k4a = SLO(1), k4b = SHI(1);
            short8 k5a = SLO(2), k5b = SHI(2);
            short8 k6a = SLO(0), k6b = SHI(0);
#pragma unroll
            for (int j = 0; j < 8; j++) {
                y[j]     += 0.022786458f * bf2f(k1a[j]) + 0.112309075f * bf2f(k3a[j])
                          + 0.162760417f * bf2f(k4a[j]) - 0.080593989f * bf2f(k5a[j])
                          + 0.032738095f * bf2f(k6a[j]);
                y[8 + j] += 0.022786458f * bf2f(k1b[j]) + 0.112309075f * bf2f(k3b[j])
                          + 0.162760417f * bf2f(k4b[j]) - 0.080593989f * bf2f(k5b[j])
                          + 0.032738095f * bf2f(k6b[j]);
            }
        }
        ylogp -= bw * d;
    }

    float nrm = 0.f;
#pragma unroll
    for (int i = 0; i < 16; i++) nrm += y[i] * y[i];
    nrm += __shfl_xor(nrm, 16, 64);
    nrm += __shfl_xor(nrm, 32, 64);
    float res = -0.5f * nrm - LOG2PI_HALF_SUM - ylogp;
    if (lane < 16) out[blockIdx.x * 64 + wave * 16 + lane] = res;
}

// ---- weight pre-shuffle: fp32 [N][K] -> bf16 fragment-linear (32x32x16) ----
// frag = ktile*NT + ntile; lane l holds W[ntile*32 + (l&31)][ktile*16 + (l>>5)*8 + 0..7]
__global__ void prep_w(const float* __restrict__ W, short* __restrict__ outp,
                       int K, int NT, int KT) {
    int slot  = blockIdx.x * 256 + threadIdx.x;
    int total = KT * NT * 64;
    if (slot >= total) return;
    int lane  = slot & 63, frag = slot >> 6;
    int ntile = frag % NT, ktile = frag / NT;
    int n = ntile * 32 + (lane & 31);
    int k = ktile * 16 + (lane >> 5) * 8;
    short8 v;
#pragma unroll
    for (int j = 0; j < 8; j++) v[j] = f2bf(W[n * K + k + j]);
    *(short8*)(outp + slot * 8) = v;
}

__global__ void prep_b(const float* __restrict__ b1, const float* __restrict__ b2,
                       const float* __restrict__ b3, const float* __restrict__ b4,
                       float* __restrict__ dst) {
    int i = blockIdx.x * 256 + threadIdx.x;
    if (i < 256)      dst[i] = b1[i];
    else if (i < 512) dst[i] = b2[i - 256];
    else if (i < 768) dst[i] = b3[i - 512];
    else if (i < 832) dst[i] = b4[i - 768];
}

extern "C" void kernel_launch(void* const* d_in, const int* in_sizes, int n_in,
                              void* d_out, int out_size, void* d_ws, size_t ws_size,
                              hipStream_t stream) {
    const float* x   = (const float*)d_in[0];
    const float* eps = (const float*)d_in[1];
    const float* W1  = (const float*)d_in[2];
    const float* b1  = (const float*)d_in[3];
    const float* W2  = (const float*)d_in[4];
    const float* b2  = (const float*)d_in[5];
    const float* W3  = (const float*)d_in[6];
    const float* b3  = (const float*)d_in[7];
    const float* W4  = (const float*)d_in[8];
    const float* b4  = (const float*)d_in[9];
    char*  ws  = (char*)d_ws;
    float* out = (float*)d_out;

    static bool attr_set = false;
    if (!attr_set) {
        hipFuncSetAttribute(reinterpret_cast<const void*>(cnf_main),
                            hipFuncAttributeMaxDynamicSharedMemorySize, SMEM_BYTES);
        attr_set = true;
    }

    // W1: 4 kt x 8 nt = 32 frags @ ws+0       (32KB)
    // W2: 16 x 8     = 128 frags @ ws+32768   (128KB)
    // W3: 16 x 8     = 128 frags @ ws+163840  (128KB)
    // W4: 16 x 2     = 32 frags @ ws+294912   (32KB)
    prep_w<<<8,  256, 0, stream>>>(W1, (short*)(ws + 0),      64,  8, 4);
    prep_w<<<32, 256, 0, stream>>>(W2, (short*)(ws + 32768),  256, 8, 16);
    prep_w<<<32, 256, 0, stream>>>(W3, (short*)(ws + 163840), 256, 8, 16);
    prep_w<<<8,  256, 0, stream>>>(W4, (short*)(ws + 294912), 256, 2, 16);
    prep_b<<<4, 256, 0, stream>>>(b1, b2, b3, b4, (float*)(ws + BOFF));

    cnf_main<<<BATCH / 64, 256, SMEM_BYTES, stream>>>(x, eps, ws, out);
}

// Round 4
// 1104.686 us; speedup vs baseline: 2.6980x; 2.6980x over previous
//
#include <hip/hip_runtime.h>

// ============================================================================
// CNF log-density, fused persistent kernel — v5.
//   - 32x32x16 MFMA with A rows 0-15 = value, rows 16-31 = tangent: one MFMA
//     computes both GEMMs (validated in v4). Tangent scale is lane-local.
//   - N-split: block = 2 groups x 2 waves; group owns 16 batch rows; wave owns
//     a 128-col half -> acc = 4 x floatx16 = 64 regs, ONE acc array live at a
//     time (activations fully transposed to group-shared LDS between layers).
//     Zero spill is the design constraint (spill poisons L2 -> round 2/3).
//   - Weights staged block-cooperatively in 16KB chunks (20/feval), prefetch
//     issued one chunk ahead into regs, ds_write after MFMA burst, 1 barrier
//     per chunk. 8 MFMAs (32x32x16) per wave per barrier.
//   - RK: v4's flattened 24-stage machine; k1/k3 bf16 in regs, k2/k4/k5/k6 in
//     3 group-shared bf16 LDS slabs.
//   - LDS 80384B -> 2 blocks/CU.
// ============================================================================

#define DIM   64
#define HID   256
#define BATCH 32768
#define LOG2PI_HALF_SUM 58.8120661251f   // 32 * log(2*pi)

typedef float  floatx4  __attribute__((ext_vector_type(4)));
typedef float  floatx16 __attribute__((ext_vector_type(16)));
typedef short  short8   __attribute__((ext_vector_type(8)));

// ---- workspace: bf16 weights, fragment-linear, contiguous 20 x 16KB chunks --
// W1 chunks 0-1, W2 2-9, W3 10-17, W4 18-19. frag = ktile*NT + ntile.
#define BOFF   327680    // biases fp32: b1[256] b2[256] b3[256] b4[64]
#define CHUNK  16384
#define NCHUNK 20

// ---- LDS ----
#define TBS         264              // shorts per tb row (256 + 8 pad)
#define TB_BYTES    16896            // 32 * 264 * 2
#define SLAB_STR    72               // shorts per slab row (64 + 8 pad)
#define SLAB_SH     1152             // shorts per slab (16*72)
#define GROUP_BYTES 23808            // tb + 3 slabs (16896 + 6912)
#define DBUF_BYTES  32768            // 2 x 16KB chunks
#define SMEM_BYTES  (DBUF_BYTES + 2 * GROUP_BYTES)   // 80384 -> 2 blocks/CU

#define MFMA32(a, b, c) __builtin_amdgcn_mfma_f32_32x32x16_bf16(a, b, c, 0, 0, 0)

__device__ __forceinline__ short f2bf(float f) {
    union { float f; unsigned u; } v; v.f = f;
    unsigned r = v.u + 0x7FFFu + ((v.u >> 16) & 1u);   // RTNE
    return (short)(r >> 16);
}

__device__ __forceinline__ float bf2f(short s) {
    union { float f; unsigned u; } v;
    v.u = ((unsigned)(unsigned short)s) << 16;
    return v.f;
}

__device__ __forceinline__ float fast_tanh(float x) {
    float e = __expf(2.0f * x);
    return 1.0f - 2.0f * __builtin_amdgcn_rcpf(e + 1.0f);
}

// ---- chunk staging: load chunk g to regs (early) / write to dbuf (late) ----
__device__ __forceinline__ void stage_ld(const char* __restrict__ ws, int g,
                                         uint4 (&r)[4]) {
    const char* p = ws + g * CHUNK + threadIdx.x * 16;
#pragma unroll
    for (int i = 0; i < 4; i++) r[i] = *(const uint4*)(p + i * 4096);
}
__device__ __forceinline__ void stage_st(char* dbuf, int g, const uint4 (&r)[4]) {
    char* p = dbuf + (g & 1) * CHUNK + threadIdx.x * 16;
#pragma unroll
    for (int i = 0; i < 4; i++) *(uint4*)(p + i * 4096) = r[i];
}

__device__ __forceinline__ floatx16 acc_init(float b) {
    floatx16 c;
#pragma unroll
    for (int r = 0; r < 8; r++) { c[r] = b; c[r + 8] = 0.f; }
    return c;
}

// acc (4 nt x 128 cols of this wave) -> tb rows 0-31 (h rows 0-15, t 16-31)
__device__ __forceinline__ void transpose_acts(const floatx16 (&acc)[4], short* tb,
                                               int sw, int l31, int hi) {
#pragma unroll
    for (int nt = 0; nt < 4; nt++) {
        const int col = sw * 128 + nt * 32 + l31;
#pragma unroll
        for (int r = 0; r < 8; r++) {
            const int rv = (r & 3) + 8 * (r >> 2) + 4 * hi;
            float h = fast_tanh(acc[nt][r]);
            float t = (1.0f - h * h) * acc[nt][r + 8];
            tb[rv * TBS + col]        = f2bf(h);
            tb[(16 + rv) * TBS + col] = f2bf(t);
        }
    }
}

// ---- one ODE f-eval: dz bf16 -> slab[sout]; returns div (all lanes) ----
__device__ __forceinline__ float feval(const float (&zs)[16], short8 e0, short8 e1,
                                       const char* __restrict__ ws, char* dbuf,
                                       short* tb, short* slabs, int sout,
                                       int lane, int m, int kq, int sw,
                                       int l31, int hi) {
    float* jb = (float*)tb;                       // overlays tb rows 0-8
    const float* bias = (const float*)(ws + BOFF);
    short* sl = slabs + sout * SLAB_SH;
    uint4 pf[4];

    // layer-1 A: sw0 writes zs rows 0-15; sw1 writes eps rows 16-31
    if (sw == 0) {
        short8 zlo, zhi;
#pragma unroll
        for (int j = 0; j < 8; j++) { zlo[j] = f2bf(zs[j]); zhi[j] = f2bf(zs[8 + j]); }
        *(short8*)&tb[m * TBS + kq * 8]      = zlo;
        *(short8*)&tb[m * TBS + 32 + kq * 8] = zhi;
    } else {
        *(short8*)&tb[(16 + m) * TBS + kq * 8]      = e0;
        *(short8*)&tb[(16 + m) * TBS + 32 + kq * 8] = e1;
    }
    __syncthreads();

    floatx16 acc[4];

    // ---------------- layer 1: K=64, chunks 0-1 ----------------
#pragma unroll
    for (int nt = 0; nt < 4; nt++) acc[nt] = acc_init(bias[sw * 128 + nt * 32 + l31]);
#pragma unroll
    for (int G = 0; G < 2; G++) {
        stage_ld(ws, G + 1, pf);
        const char* bp = dbuf + (G & 1) * CHUNK;
#pragma unroll
        for (int ktl = 0; ktl < 2; ktl++) {
            const int kt = G * 2 + ktl;
            short8 a = *(const short8*)&tb[l31 * TBS + kt * 16 + hi * 8];
#pragma unroll
            for (int nt = 0; nt < 4; nt++) {
                short8 b = *(const short8*)(bp + (ktl * 8 + sw * 4 + nt) * 1024 + lane * 16);
                acc[nt] = MFMA32(a, b, acc[nt]);
            }
        }
        stage_st(dbuf, G + 1, pf);
        __syncthreads();
    }
    transpose_acts(acc, tb, sw, l31, hi);
    __syncthreads();

    // ---------------- layers 2,3: K=256, chunks 2-9 / 10-17 ----------------
#pragma unroll 1
    for (int layer = 0; layer < 2; layer++) {
        const int gb = 2 + layer * 8;
        const float* bb = bias + 256 + layer * 256;
#pragma unroll
        for (int nt = 0; nt < 4; nt++) acc[nt] = acc_init(bb[sw * 128 + nt * 32 + l31]);
#pragma unroll
        for (int c = 0; c < 8; c++) {
            const int G = gb + c;
            stage_ld(ws, G + 1, pf);
            const char* bp = dbuf + (G & 1) * CHUNK;
#pragma unroll
            for (int ktl = 0; ktl < 2; ktl++) {
                const int kt = c * 2 + ktl;
                short8 a = *(const short8*)&tb[l31 * TBS + kt * 16 + hi * 8];
#pragma unroll
                for (int nt = 0; nt < 4; nt++) {
                    short8 b = *(const short8*)(bp + (ktl * 8 + sw * 4 + nt) * 1024 + lane * 16);
                    acc[nt] = MFMA32(a, b, acc[nt]);
                }
            }
            stage_st(dbuf, G + 1, pf);
            __syncthreads();
        }
        transpose_acts(acc, tb, sw, l31, hi);
        __syncthreads();
    }

    // ---------------- layer 4: K=256, N=64 (wave: 32 cols), chunks 18-19 ----
    floatx16 a4 = acc_init(bias[768 + sw * 32 + l31]);
#pragma unroll
    for (int c = 0; c < 2; c++) {
        const int G = 18 + c;
        const int gn = (G + 1 == NCHUNK) ? 0 : G + 1;   // wrap: next feval chunk 0
        stage_ld(ws, gn, pf);
        const char* bp = dbuf + (G & 1) * CHUNK;
#pragma unroll
        for (int ktl = 0; ktl < 8; ktl++) {
            const int kt = c * 8 + ktl;
            short8 a = *(const short8*)&tb[l31 * TBS + kt * 16 + hi * 8];
            short8 b = *(const short8*)(bp + (ktl * 2 + sw) * 1024 + lane * 16);
            a4 = MFMA32(a, b, a4);
        }
        stage_st(dbuf, gn, pf);
        __syncthreads();
    }

    // ---- epilogue: Jeps fp32 -> jb; dz bf16 -> slab[sout] ----
#pragma unroll
    for (int r = 0; r < 8; r++) {
        const int rv = (r & 3) + 8 * (r >> 2) + 4 * hi;
        jb[rv * 68 + sw * 32 + l31]       = a4[r + 8];
        sl[rv * SLAB_STR + sw * 32 + l31] = f2bf(a4[r]);
    }
    __syncthreads();
    float div = 0.f;
#pragma unroll
    for (int q = 0; q < 2; q++) {
        floatx4 j0 = *(const floatx4*)&jb[m * 68 + kq * 8 + q * 4];
        floatx4 j1 = *(const floatx4*)&jb[m * 68 + 32 + kq * 8 + q * 4];
#pragma unroll
        for (int j = 0; j < 4; j++)
            div += j0[j] * bf2f(e0[q * 4 + j]) + j1[j] * bf2f(e1[q * 4 + j]);
    }
    div += __shfl_xor(div, 16, 64);
    div += __shfl_xor(div, 32, 64);
    __syncthreads();                    // jb dead before next feval's tb writes
    return div;
}

#define SLO(s) (*(const short8*)&slabs[(s) * SLAB_SH + m * SLAB_STR + kq * 8])
#define SHI(s) (*(const short8*)&slabs[(s) * SLAB_SH + m * SLAB_STR + 32 + kq * 8])

__global__ void __launch_bounds__(256, 2)
cnf_main(const float* __restrict__ x, const float* __restrict__ eps,
         const char* __restrict__ ws, float* __restrict__ out) {
    extern __shared__ char smem[];
    const int tid  = threadIdx.x;
    const int lane = tid & 63;
    const int wave = tid >> 6;
    const int group = wave >> 1, sw = wave & 1;
    const int m = lane & 15, kq = lane >> 4;
    const int l31 = lane & 31, hi = lane >> 5;
    char*  dbuf  = smem;
    short* tb    = (short*)(smem + DBUF_BYTES + group * GROUP_BYTES);
    short* slabs = (short*)(smem + DBUF_BYTES + group * GROUP_BYTES + TB_BYTES);
    const int row = blockIdx.x * 32 + group * 16 + m;

    float y[16];
    short8 e0, e1;
#pragma unroll
    for (int kt = 0; kt < 2; kt++)
#pragma unroll
        for (int q = 0; q < 2; q++) {
            floatx4 vx = *(const floatx4*)(x   + row * DIM + kt * 32 + kq * 8 + q * 4);
            floatx4 ve = *(const floatx4*)(eps + row * DIM + kt * 32 + kq * 8 + q * 4);
#pragma unroll
            for (int j = 0; j < 4; j++) {
                y[kt * 8 + q * 4 + j] = vx[j];
                short b = f2bf(ve[j]);
                if (kt == 0) e0[q * 4 + j] = b; else e1[q * 4 + j] = b;
            }
        }

    // zero both groups' slabs (0-coeff combines must not FMA NaN garbage)
    {
        short8 z = {0, 0, 0, 0, 0, 0, 0, 0};
#pragma unroll
        for (int g = 0; g < 2; g++) {
            short* sb = (short*)(smem + DBUF_BYTES + g * GROUP_BYTES + TB_BYTES);
            for (int k = tid; k < 432; k += 256) *(short8*)&sb[k * 8] = z;
        }
    }

    // prologue: stage chunk 0 (feval's first barrier publishes it)
    {
        uint4 pf[4];
        stage_ld(ws, 0, pf);
        stage_st(dbuf, 0, pf);
    }

    float ylogp = 0.f;
    short8 zero8 = {0, 0, 0, 0, 0, 0, 0, 0};
    short8 k1a = zero8, k1b = zero8, k3a = zero8, k3b = zero8;

#pragma unroll 1
    for (int st = 0; st < 24; st++) {
        const int stage = st % 6;
        float c1, c2, c3, c4, c5, bw; int sout;
        switch (stage) {
            case 0: c1=0.f;           c2=0.f;            c3=0.f;           c4=0.f;            c5=0.f;            bw=0.022786458f;  sout=0; break;
            case 1: c1=0.05f;         c2=0.f;            c3=0.f;           c4=0.f;            c5=0.f;            bw=0.f;           sout=0; break;
            case 2: c1=0.01875f;      c2=0.05625f;       c3=0.f;           c4=0.f;            c5=0.f;            bw=0.112309075f;  sout=1; break;
            case 3: c1=0.244444444f;  c2=-0.933333333f;  c3=0.888888889f;  c4=0.f;            c5=0.f;            bw=0.162760417f;  sout=1; break;
            case 4: c1=0.738149672f;  c2=-2.898948331f;  c3=2.455723213f;  c4=-0.072702332f;  c5=0.f;            bw=-0.080593989f; sout=2; break;
            default:c1=0.711568813f;  c2=-2.689393939f;  c3=2.226605679f;  c4=0.069602273f;   c5=-0.068382826f;  bw=0.032738095f;  sout=0; break;
        }

        // zs = y + c1 k1(regs) + c2 slab0 + c3 k3(regs) + c4 slab1 + c5 slab2
        float zs[16];
        {
            short8 k2a = SLO(0), k2b = SHI(0);
            short8 k4a = SLO(1), k4b = SHI(1);
            short8 k5a = SLO(2), k5b = SHI(2);
#pragma unroll
            for (int j = 0; j < 8; j++) {
                zs[j]     = y[j]     + c1 * bf2f(k1a[j]) + c2 * bf2f(k2a[j])
                                     + c3 * bf2f(k3a[j]) + c4 * bf2f(k4a[j])
                                     + c5 * bf2f(k5a[j]);
                zs[8 + j] = y[8 + j] + c1 * bf2f(k1b[j]) + c2 * bf2f(k2b[j])
                                     + c3 * bf2f(k3b[j]) + c4 * bf2f(k4b[j])
                                     + c5 * bf2f(k5b[j]);
            }
        }

        const float d = feval(zs, e0, e1, ws, dbuf, tb, slabs, sout,
                              lane, m, kq, sw, l31, hi);

        if (stage == 0) { k1a = SLO(0); k1b = SHI(0); }   // k1 -> regs (slot 0 -> k2)
        if (stage == 2) { k3a = SLO(1); k3b = SHI(1); }   // k3 -> regs (slot 1 -> k4)
        if (stage == 5) {
            // y += b1 k1 + b3 k3 + b4 slab1 + b5 slab2 + b6 slab0
            short8 k4a = SLO(1), k4b = SHI(1);
            short8 k5a = SLO(2), k5b = SHI(2);
            short8 k6a = SLO(0), k6b = SHI(0);
#pragma unroll
            for (int j = 0; j < 8; j++) {
                y[j]     += 0.022786458f * bf2f(k1a[j]) + 0.112309075f * bf2f(k3a[j])
                          + 0.162760417f * bf2f(k4a[j]) - 0.080593989f * bf2f(k5a[j])
                          + 0.032738095f * bf2f(k6a[j]);
                y[8 + j] += 0.022786458f * bf2f(k1b[j]) + 0.112309075f * bf2f(k3b[j])
                          + 0.162760417f * bf2f(k4b[j]) - 0.080593989f * bf2f(k5b[j])
                          + 0.032738095f * bf2f(k6b[j]);
            }
        }
        ylogp -= bw * d;
    }

    float nrm = 0.f;
#pragma unroll
    for (int i = 0; i < 16; i++) nrm += y[i] * y[i];
    nrm += __shfl_xor(nrm, 16, 64);
    nrm += __shfl_xor(nrm, 32, 64);
    float res = -0.5f * nrm - LOG2PI_HALF_SUM - ylogp;
    if (sw == 0 && lane < 16) out[blockIdx.x * 32 + group * 16 + lane] = res;
}

// ---- weight pre-shuffle: fp32 [N][K] -> bf16 fragment-linear (32x32x16) ----
// frag = ktile*NT + ntile; lane l holds W[ntile*32 + (l&31)][ktile*16 + (l>>5)*8 + 0..7]
__global__ void prep_w(const float* __restrict__ W, short* __restrict__ outp,
                       int K, int NT, int KT) {
    int slot  = blockIdx.x * 256 + threadIdx.x;
    int total = KT * NT * 64;
    if (slot >= total) return;
    int lane  = slot & 63, frag = slot >> 6;
    int ntile = frag % NT, ktile = frag / NT;
    int n = ntile * 32 + (lane & 31);
    int k = ktile * 16 + (lane >> 5) * 8;
    short8 v;
#pragma unroll
    for (int j = 0; j < 8; j++) v[j] = f2bf(W[n * K + k + j]);
    *(short8*)(outp + slot * 8) = v;
}

__global__ void prep_b(const float* __restrict__ b1, const float* __restrict__ b2,
                       const float* __restrict__ b3, const float* __restrict__ b4,
                       float* __restrict__ dst) {
    int i = blockIdx.x * 256 + threadIdx.x;
    if (i < 256)      dst[i] = b1[i];
    else if (i < 512) dst[i] = b2[i - 256];
    else if (i < 768) dst[i] = b3[i - 512];
    else if (i < 832) dst[i] = b4[i - 768];
}

extern "C" void kernel_launch(void* const* d_in, const int* in_sizes, int n_in,
                              void* d_out, int out_size, void* d_ws, size_t ws_size,
                              hipStream_t stream) {
    const float* x   = (const float*)d_in[0];
    const float* eps = (const float*)d_in[1];
    const float* W1  = (const float*)d_in[2];
    const float* b1  = (const float*)d_in[3];
    const float* W2  = (const float*)d_in[4];
    const float* b2  = (const float*)d_in[5];
    const float* W3  = (const float*)d_in[6];
    const float* b3  = (const float*)d_in[7];
    const float* W4  = (const float*)d_in[8];
    const float* b4  = (const float*)d_in[9];
    char*  ws  = (char*)d_ws;
    float* out = (float*)d_out;

    static bool attr_set = false;
    if (!attr_set) {
        hipFuncSetAttribute(reinterpret_cast<const void*>(cnf_main),
                            hipFuncAttributeMaxDynamicSharedMemorySize, SMEM_BYTES);
        attr_set = true;
    }

    // W1: KT=4, NT=8  -> 32 frags  @ ws+0       (32KB,  chunks 0-1)
    // W2: KT=16,NT=8  -> 128 frags @ ws+32768   (128KB, chunks 2-9)
    // W3: KT=16,NT=8  -> 128 frags @ ws+163840  (128KB, chunks 10-17)
    // W4: KT=16,NT=2  -> 32 frags  @ ws+294912  (32KB,  chunks 18-19)
    prep_w<<<8,  256, 0, stream>>>(W1, (short*)(ws + 0),      64,  8, 4);
    prep_w<<<32, 256, 0, stream>>>(W2, (short*)(ws + 32768),  256, 8, 16);
    prep_w<<<32, 256, 0, stream>>>(W3, (short*)(ws + 163840), 256, 8, 16);
    prep_w<<<8,  256, 0, stream>>>(W4, (short*)(ws + 294912), 256, 2, 16);
    prep_b<<<4, 256, 0, stream>>>(b1, b2, b3, b4, (float*)(ws + BOFF));

    cnf_main<<<BATCH / 32, 256, SMEM_BYTES, stream>>>(x, eps, ws, out);
}